// Round 9
// baseline (651.839 us; speedup 1.0000x reference)
//
#include <hip/hip_runtime.h>
#include <stdint.h>
#include <math.h>

#define VV 128000
#define DD 2048
#define BB 32
#define SS 8
#define CH 64          // floats per K-chunk
#define NCH (DD / CH)  // 32 chunks
#define NCAND 4096

// jax_threefry_partitionable 32-bit stream: counter=(0,flat), bits = o0 ^ o1.  (verified R4/R5)

// direct global->LDS (no VGPR round-trip); dest = wave-uniform base + lane*16
#define GLDS(src, dst) __builtin_amdgcn_global_load_lds( \
    (const __attribute__((address_space(1))) void*)(src), \
    (__attribute__((address_space(3))) void*)(dst), 16, 0, 0)

// ---------------- threefry2x32 core (key = (0, 42) from jax.random.key(42)) ----------------
__device__ __forceinline__ uint32_t rotl32(uint32_t x, uint32_t r) {
    return (x << r) | (x >> (32u - r));
}

__device__ __forceinline__ void threefry2x32(uint32_t c0, uint32_t c1,
                                             uint32_t& o0, uint32_t& o1) {
    const uint32_t k0 = 0u, k1 = 42u;
    const uint32_t k2 = 0x1BD11BDAu ^ k0 ^ k1;
    uint32_t x0 = c0 + k0;
    uint32_t x1 = c1 + k1;
    #define TF_ROUND(r) { x0 += x1; x1 = rotl32(x1, r); x1 ^= x0; }
    TF_ROUND(13) TF_ROUND(15) TF_ROUND(26) TF_ROUND(6)
    x0 += k1; x1 += k2 + 1u;
    TF_ROUND(17) TF_ROUND(29) TF_ROUND(16) TF_ROUND(24)
    x0 += k2; x1 += k0 + 2u;
    TF_ROUND(13) TF_ROUND(15) TF_ROUND(26) TF_ROUND(6)
    x0 += k0; x1 += k1 + 3u;
    TF_ROUND(17) TF_ROUND(29) TF_ROUND(16) TF_ROUND(24)
    x0 += k1; x1 += k2 + 4u;
    TF_ROUND(13) TF_ROUND(15) TF_ROUND(26) TF_ROUND(6)
    x0 += k2; x1 += k0 + 5u;
    #undef TF_ROUND
    o0 = x0; o1 = x1;
}

__device__ float gumbel_at(uint32_t flat) {
    uint32_t o0, o1;
    threefry2x32(0u, flat, o0, o1);   // counter (hi=0, lo=flat)
    uint32_t bits = o0 ^ o1;          // partitionable 32-bit path
    uint32_t fb = (bits >> 9) | 0x3F800000u;
    float f = __uint_as_float(fb) - 1.0f;
    const float TINY = 1.17549435e-38f;
    float u = (f > 0.0f) ? f : TINY;
    return -logf(-logf(u));
}

__device__ __forceinline__ uint32_t enc_f32(float f) {
    uint32_t u = __float_as_uint(f);
    return u ^ (0x80000000u | (uint32_t)(((int32_t)u) >> 31));  // order-preserving
}

// ---------------- K1: logits = softcap(hs @ emb^T)/temp ----------------
// Block: 512 threads = 8 waves; 16 v-rows x 32 batches per block.
// Wave w owns batches w*4..w*4+3; stages its own hidden rows (wave-private
// 3-slot LDS ring via global_load_lds, staged 2 ahead, NO __syncthreads in
// the K-loop). e-stream: ping-pong eA/eB register double-buffer, chunk c+1
// issued before chunk c's FMAs (hand-unrolled x2, zero moves).
// Every half-iter issues EXACTLY 5 vmem ops (4 e + 1 GLDS; tails clamp the
// address instead of skipping) -> invariant s_waitcnt vmcnt(10) guarantees
// stage(c) retired (10 = the two younger half-iters' ops).
// FMA k-order per acc element identical to R8 (bit-identical logits/tokens).
__global__ __launch_bounds__(512, 4) void gemv_kernel(
    const float* __restrict__ emb, const float* __restrict__ hidden,
    const int* __restrict__ outpos, const float* __restrict__ temps,
    float* __restrict__ out)
{
    __shared__ float hs[3][BB][CH];    // 24 KB ring
    __shared__ float lout[16][33];     // epilogue transpose

    const int tid   = threadIdx.x;
    const int w     = tid >> 6;        // wave 0..7
    const int lane  = tid & 63;
    const int kl    = lane & 15;
    const int vl    = lane >> 4;       // 0..3
    const int vbase = blockIdx.x * 16;
    const int pos   = outpos[0];
    const int bb0   = w << 2;          // this wave's 4 batches

    const float* hbase  = hidden + (size_t)pos * DD;
    const float* gstage = hbase + (size_t)(bb0 + vl) * (SS * DD) + (kl << 2);
    const float* ebase  = emb + (size_t)(vbase + (vl << 2)) * DD + (kl << 2);

    float acc[4][4];
    #pragma unroll
    for (int v = 0; v < 4; ++v)
        #pragma unroll
        for (int b = 0; b < 4; ++b) acc[v][b] = 0.0f;

    // prologue: stage chunks 0,1; preload e chunk 0   (order matters for vmcnt)
    GLDS(gstage,      &hs[0][bb0][0]);
    GLDS(gstage + CH, &hs[1][bb0][0]);
    float4 eA0 = *reinterpret_cast<const float4*>(ebase + 0 * DD);
    float4 eA1 = *reinterpret_cast<const float4*>(ebase + 1 * DD);
    float4 eA2 = *reinterpret_cast<const float4*>(ebase + 2 * DD);
    float4 eA3 = *reinterpret_cast<const float4*>(ebase + 3 * DD);
    float4 eB0, eB1, eB2, eB3;

    int rb = 0, wb = 2;

    // one half-iteration: prefetch NXT = e(C+1), stage chunk C+2 (clamped),
    // wait, ds_read h(C) interleaved with FMAs consuming CUR = e(C).
    #define HALF(C, C0,C1,C2,C3, N0,N1,N2,N3) \
    { \
        const float* enx = ebase + (size_t)(((C) + 1) & 31) * CH; \
        N0 = *reinterpret_cast<const float4*>(enx + 0 * DD); \
        N1 = *reinterpret_cast<const float4*>(enx + 1 * DD); \
        N2 = *reinterpret_cast<const float4*>(enx + 2 * DD); \
        N3 = *reinterpret_cast<const float4*>(enx + 3 * DD); \
        { const float* s = ((C) < NCH - 2) ? (gstage + (size_t)((C) + 2) * CH) \
                                           : gstage; \
          GLDS(s, &hs[wb][bb0][0]); } \
        asm volatile("s_waitcnt vmcnt(10)" ::: "memory"); \
        float4 h0 = *reinterpret_cast<const float4*>(&hs[rb][bb0 + 0][kl << 2]); \
        float4 h1 = *reinterpret_cast<const float4*>(&hs[rb][bb0 + 1][kl << 2]); \
        acc[0][0] += C0.x * h0.x; acc[0][0] += C0.y * h0.y; \
        acc[0][0] += C0.z * h0.z; acc[0][0] += C0.w * h0.w; \
        acc[1][0] += C1.x * h0.x; acc[1][0] += C1.y * h0.y; \
        acc[1][0] += C1.z * h0.z; acc[1][0] += C1.w * h0.w; \
        acc[2][0] += C2.x * h0.x; acc[2][0] += C2.y * h0.y; \
        acc[2][0] += C2.z * h0.z; acc[2][0] += C2.w * h0.w; \
        acc[3][0] += C3.x * h0.x; acc[3][0] += C3.y * h0.y; \
        acc[3][0] += C3.z * h0.z; acc[3][0] += C3.w * h0.w; \
        float4 h2 = *reinterpret_cast<const float4*>(&hs[rb][bb0 + 2][kl << 2]); \
        acc[0][1] += C0.x * h1.x; acc[0][1] += C0.y * h1.y; \
        acc[0][1] += C0.z * h1.z; acc[0][1] += C0.w * h1.w; \
        acc[1][1] += C1.x * h1.x; acc[1][1] += C1.y * h1.y; \
        acc[1][1] += C1.z * h1.z; acc[1][1] += C1.w * h1.w; \
        acc[2][1] += C2.x * h1.x; acc[2][1] += C2.y * h1.y; \
        acc[2][1] += C2.z * h1.z; acc[2][1] += C2.w * h1.w; \
        acc[3][1] += C3.x * h1.x; acc[3][1] += C3.y * h1.y; \
        acc[3][1] += C3.z * h1.z; acc[3][1] += C3.w * h1.w; \
        float4 h3 = *reinterpret_cast<const float4*>(&hs[rb][bb0 + 3][kl << 2]); \
        acc[0][2] += C0.x * h2.x; acc[0][2] += C0.y * h2.y; \
        acc[0][2] += C0.z * h2.z; acc[0][2] += C0.w * h2.w; \
        acc[1][2] += C1.x * h2.x; acc[1][2] += C1.y * h2.y; \
        acc[1][2] += C1.z * h2.z; acc[1][2] += C1.w * h2.w; \
        acc[2][2] += C2.x * h2.x; acc[2][2] += C2.y * h2.y; \
        acc[2][2] += C2.z * h2.z; acc[2][2] += C2.w * h2.w; \
        acc[3][2] += C3.x * h2.x; acc[3][2] += C3.y * h2.y; \
        acc[3][2] += C3.z * h2.z; acc[3][2] += C3.w * h2.w; \
        acc[0][3] += C0.x * h3.x; acc[0][3] += C0.y * h3.y; \
        acc[0][3] += C0.z * h3.z; acc[0][3] += C0.w * h3.w; \
        acc[1][3] += C1.x * h3.x; acc[1][3] += C1.y * h3.y; \
        acc[1][3] += C1.z * h3.z; acc[1][3] += C1.w * h3.w; \
        acc[2][3] += C2.x * h3.x; acc[2][3] += C2.y * h3.y; \
        acc[2][3] += C2.z * h3.z; acc[2][3] += C2.w * h3.w; \
        acc[3][3] += C3.x * h3.x; acc[3][3] += C3.y * h3.y; \
        acc[3][3] += C3.z * h3.z; acc[3][3] += C3.w * h3.w; \
        rb = (rb == 2) ? 0 : rb + 1; \
        wb = (wb == 2) ? 0 : wb + 1; \
    }

    #pragma unroll 1
    for (int d = 0; d < NCH / 2; ++d) {
        const int c0 = 2 * d;
        HALF(c0,     eA0, eA1, eA2, eA3, eB0, eB1, eB2, eB3)
        HALF(c0 + 1, eB0, eB1, eB2, eB3, eA0, eA1, eA2, eA3)
    }
    #undef HALF

    // reduce partial dots across the 16 k-lanes (identical tree to R8)
    #pragma unroll
    for (int v = 0; v < 4; ++v)
        #pragma unroll
        for (int b = 0; b < 4; ++b) {
            float a = acc[v][b];
            a += __shfl_xor(a, 1, 64);
            a += __shfl_xor(a, 2, 64);
            a += __shfl_xor(a, 4, 64);
            a += __shfl_xor(a, 8, 64);
            acc[v][b] = a;
        }

    if (kl == 0) {
        #pragma unroll
        for (int v = 0; v < 4; ++v)
            #pragma unroll
            for (int b = 0; b < 4; ++b) {
                float raw = acc[v][b];
                float l = tanhf(raw / 30.0f) * 30.0f;   // final logit softcapping
                l = l / temps[bb0 + b];                  // temperature
                lout[(vl << 2) + v][bb0 + b] = l;
            }
    }
    __syncthreads();
    // coalesced store: 512 logits, one per thread
    {
        int b2  = tid >> 4;
        int vv2 = tid & 15;
        out[32 + (size_t)b2 * VV + vbase + vv2] = lout[vv2][b2];
    }
}

// ---------------- K2: per-row top-64 (prob-sorted, stable) + exact-RNG categorical ----------------
__global__ __launch_bounds__(1024) void sample_kernel(
    float* __restrict__ dout, const float* __restrict__ top_ps,
    const int* __restrict__ top_ks)
{
    const int b   = blockIdx.x;
    const int tid = threadIdx.x;
    const float* row = dout + 32 + (size_t)b * VV;

    __shared__ unsigned int hist[2048];            // 8KB
    __shared__ unsigned long long arr[NCAND];      // 32KB: (enc(p)<<32)|~idx
    __shared__ float red[1024];                    // 4KB
    __shared__ float m_sh;
    __shared__ unsigned int thresh_sh;
    __shared__ unsigned int cnt_sh;
    __shared__ float p_arr[64];
    __shared__ unsigned int idx_arr[64];
    __shared__ float S_sh;
    __shared__ unsigned long long keep_sh;

    for (int i = tid; i < 2048; i += 1024) hist[i] = 0u;
    for (int i = tid; i < NCAND; i += 1024) arr[i] = 0ull;
    if (tid == 0) cnt_sh = 0u;
    __syncthreads();

    // ---- pass A: row max + 11-bit float-order histogram ----
    float lmax = -INFINITY;
    for (int i = tid; i < VV; i += 1024) {
        float l = row[i];
        lmax = fmaxf(lmax, l);
        atomicAdd(&hist[enc_f32(l) >> 21], 1u);
    }
    red[tid] = lmax;
    __syncthreads();
    for (int s = 512; s > 0; s >>= 1) {
        if (tid < s) red[tid] = fmaxf(red[tid], red[tid + s]);
        __syncthreads();
    }
    if (tid == 0) {
        float m = red[0];
        m_sh = m;
        int t = (int)(enc_f32(m) >> 21);
        unsigned int cum = 0u;
        for (; t >= 0; --t) { cum += hist[t]; if (cum >= 64u) break; }
        if (t < 0) t = 0;
        thresh_sh = ((unsigned int)t) << 21;
    }
    __syncthreads();
    const float m = m_sh;
    const unsigned int thresh = thresh_sh;

    // ---- pass B: softmax denominator Z ----
    float z = 0.0f;
    for (int i = tid; i < VV; i += 1024) z += expf(row[i] - m);
    red[tid] = z;
    __syncthreads();
    for (int s = 512; s > 0; s >>= 1) {
        if (tid < s) red[tid] += red[tid + s];
        __syncthreads();
    }
    const float Z = red[0];
    __syncthreads();

    // ---- pass C: collect candidates keyed by (prob desc, idx asc) ----
    for (int i = tid; i < VV; i += 1024) {
        float l = row[i];
        if (enc_f32(l) >= thresh) {
            float p = expf(l - m) / Z;
            unsigned int slot = atomicAdd(&cnt_sh, 1u);
            if (slot < NCAND)
                arr[slot] = ((unsigned long long)enc_f32(p) << 32)
                          | (unsigned long long)(~(unsigned int)i);
        }
    }
    __syncthreads();

    // ---- bitonic sort, descending (zeros sink to the end) ----
    for (int k = 2; k <= NCAND; k <<= 1) {
        for (int j = k >> 1; j > 0; j >>= 1) {
            for (int t = tid; t < NCAND; t += 1024) {
                int ixj = t ^ j;
                if (ixj > t) {
                    unsigned long long a = arr[t], c = arr[ixj];
                    bool desc = ((t & k) == 0);
                    if (desc ? (a < c) : (a > c)) { arr[t] = c; arr[ixj] = a; }
                }
            }
            __syncthreads();
        }
    }

    // ---- decode top-64 ----
    if (tid < 64) {
        unsigned long long key = arr[tid];
        p_arr[tid]   = __uint_as_float((unsigned int)(key >> 32) & 0x7FFFFFFFu);
        idx_arr[tid] = ~((unsigned int)(key & 0xFFFFFFFFull));
    }
    __syncthreads();

    // ---- sequential fp32 cumsum + top-p/top-k keep mask (np order) ----
    if (tid == 0) {
        float cum = 0.0f, S = 0.0f;
        unsigned long long keep = 0ull;
        const float tp = top_ps[b];
        const int   tk = top_ks[b];
        for (int r = 0; r < 64; ++r) {
            float p = p_arr[r];
            cum = cum + p;
            float excl = cum - p;
            if (!(excl > tp) && (r < tk)) { keep |= (1ull << r); S = S + p; }
        }
        S_sh = S; keep_sh = keep;
    }
    __syncthreads();

    // ---- gumbel-max over kept set (exact jax.random.categorical(key(42))) ----
    if (tid < 64) {
        unsigned long long pk = 0ull;
        if ((keep_sh >> tid) & 1ull) {
            float q  = p_arr[tid] / S_sh;
            float lp = logf(q);
            unsigned int idx = idx_arr[tid];
            float g = gumbel_at((unsigned int)b * (unsigned int)VV + idx);
            float vf = lp + g;
            pk = ((unsigned long long)enc_f32(vf) << 32)
               | (unsigned long long)(~idx);
        }
        for (int off = 1; off < 64; off <<= 1) {
            unsigned long long o = __shfl_xor(pk, off, 64);
            if (o > pk) pk = o;
        }
        if (tid == 0) {
            unsigned int token = ~((unsigned int)(pk & 0xFFFFFFFFull));
            dout[b] = (float)token;
        }
    }
}

extern "C" void kernel_launch(void* const* d_in, const int* in_sizes, int n_in,
                              void* d_out, int out_size, void* d_ws, size_t ws_size,
                              hipStream_t stream) {
    const float* emb   = (const float*)d_in[0];
    const float* hid   = (const float*)d_in[1];
    const int*   pos   = (const int*)d_in[2];
    const float* temps = (const float*)d_in[3];
    const float* tps   = (const float*)d_in[4];
    const int*   tks   = (const int*)d_in[5];
    float* out = (float*)d_out;

    gemv_kernel<<<dim3(VV / 16), dim3(512), 0, stream>>>(emb, hid, pos, temps, out);
    sample_kernel<<<dim3(BB), dim3(1024), 0, stream>>>(out, tps, tks);
}

// Round 10
// 643.279 us; speedup vs baseline: 1.0133x; 1.0133x over previous
//
#include <hip/hip_runtime.h>
#include <stdint.h>
#include <math.h>

#define VV 128000
#define DD 2048
#define BB 32
#define SS 8
#define CHF 128        // floats per K-chunk
#define NCH (DD / CHF) // 16 chunks
#define NCAND 4096

// jax_threefry_partitionable 32-bit stream: counter=(0,flat), bits = o0 ^ o1.  (verified R4/R5)

// direct global->LDS; dest = wave-uniform base + lane*16, src per-lane
#define GLDS(src, dst) __builtin_amdgcn_global_load_lds( \
    (const __attribute__((address_space(1))) void*)(src), \
    (__attribute__((address_space(3))) void*)(dst), 16, 0, 0)
#define CBAR() asm volatile("" ::: "memory")   // compiler-only ordering fence

// ---------------- threefry2x32 core (key = (0, 42) from jax.random.key(42)) ----------------
__device__ __forceinline__ uint32_t rotl32(uint32_t x, uint32_t r) {
    return (x << r) | (x >> (32u - r));
}

__device__ __forceinline__ void threefry2x32(uint32_t c0, uint32_t c1,
                                             uint32_t& o0, uint32_t& o1) {
    const uint32_t k0 = 0u, k1 = 42u;
    const uint32_t k2 = 0x1BD11BDAu ^ k0 ^ k1;
    uint32_t x0 = c0 + k0;
    uint32_t x1 = c1 + k1;
    #define TF_ROUND(r) { x0 += x1; x1 = rotl32(x1, r); x1 ^= x0; }
    TF_ROUND(13) TF_ROUND(15) TF_ROUND(26) TF_ROUND(6)
    x0 += k1; x1 += k2 + 1u;
    TF_ROUND(17) TF_ROUND(29) TF_ROUND(16) TF_ROUND(24)
    x0 += k2; x1 += k0 + 2u;
    TF_ROUND(13) TF_ROUND(15) TF_ROUND(26) TF_ROUND(6)
    x0 += k0; x1 += k1 + 3u;
    TF_ROUND(17) TF_ROUND(29) TF_ROUND(16) TF_ROUND(24)
    x0 += k1; x1 += k2 + 4u;
    TF_ROUND(13) TF_ROUND(15) TF_ROUND(26) TF_ROUND(6)
    x0 += k2; x1 += k0 + 5u;
    #undef TF_ROUND
    o0 = x0; o1 = x1;
}

__device__ float gumbel_at(uint32_t flat) {
    uint32_t o0, o1;
    threefry2x32(0u, flat, o0, o1);   // counter (hi=0, lo=flat)
    uint32_t bits = o0 ^ o1;          // partitionable 32-bit path
    uint32_t fb = (bits >> 9) | 0x3F800000u;
    float f = __uint_as_float(fb) - 1.0f;
    const float TINY = 1.17549435e-38f;
    float u = (f > 0.0f) ? f : TINY;
    return -logf(-logf(u));
}

__device__ __forceinline__ uint32_t enc_f32(float f) {
    uint32_t u = __float_as_uint(f);
    return u ^ (0x80000000u | (uint32_t)(((int32_t)u) >> 31));  // order-preserving
}

// ---------------- K1: logits = softcap(hs @ emb^T)/temp ----------------
// 512 thr = 8 waves; 16 v-rows x 32 batches per block; wave w owns batches
// w*4..w*4+3 (wave-private LDS ring, NO K-loop barriers).
// CHF=128: per iter 8 e-loads (prefetch chunk c+1) + 2 GLDS (stage c+2) = 10
// vmem ops, uniform every iter (tail wrap/clamp + keep-alives). vmcnt(20) =
// 2 younger iters' ops => stage(c) retired; e(c) covered by a full SIMD round
// (~1300cy > ~900cy HBM). FMA k-order per acc element identical to R8/R9.
__global__ __launch_bounds__(512, 4) void gemv_kernel(
    const float* __restrict__ emb, const float* __restrict__ hidden,
    const int* __restrict__ outpos, const float* __restrict__ temps,
    float* __restrict__ out)
{
    __shared__ float hs[3][BB][CHF];   // 48 KB ring
    __shared__ float lout[16][33];     // epilogue transpose

    const int tid   = threadIdx.x;
    const int w     = tid >> 6;        // wave 0..7
    const int lane  = tid & 63;
    const int kl    = lane & 15;
    const int vl    = lane >> 4;       // 0..3
    const int vbase = blockIdx.x * 16;
    const int pos   = outpos[0];
    const int bb0   = w << 2;          // this wave's 4 batches

    const float* hbase = hidden + (size_t)pos * DD;
    // stage sources: GLDS A covers rows bb0,bb0+1; B covers bb0+2,bb0+3
    const float* gsrcA = hbase + (size_t)(bb0 + (lane >> 5)) * (SS * DD) + ((lane & 31) << 2);
    const float* gsrcB = gsrcA + (size_t)2 * (SS * DD);
    const float* ebase = emb + (size_t)(vbase + (vl << 2)) * DD + (kl << 2);

    float acc[4][4];
    #pragma unroll
    for (int v = 0; v < 4; ++v)
        #pragma unroll
        for (int b = 0; b < 4; ++b) acc[v][b] = 0.0f;

    // prologue: stage chunks 0,1 (4 GLDS), then e(0) x8  (queue order pinned)
    GLDS(gsrcA,       &hs[0][bb0][0]);
    GLDS(gsrcB,       &hs[0][bb0 + 2][0]);
    GLDS(gsrcA + CHF, &hs[1][bb0][0]);
    GLDS(gsrcB + CHF, &hs[1][bb0 + 2][0]);
    CBAR();
    float4 A00 = *reinterpret_cast<const float4*>(ebase + 0 * DD);
    float4 A01 = *reinterpret_cast<const float4*>(ebase + 0 * DD + 64);
    float4 A10 = *reinterpret_cast<const float4*>(ebase + 1 * DD);
    float4 A11 = *reinterpret_cast<const float4*>(ebase + 1 * DD + 64);
    float4 A20 = *reinterpret_cast<const float4*>(ebase + 2 * DD);
    float4 A21 = *reinterpret_cast<const float4*>(ebase + 2 * DD + 64);
    float4 A30 = *reinterpret_cast<const float4*>(ebase + 3 * DD);
    float4 A31 = *reinterpret_cast<const float4*>(ebase + 3 * DD + 64);
    float4 B00, B01, B10, B11, B20, B21, B30, B31;
    CBAR();

    int rb = 0, wb = 2;

    #define PASSF(HB, E0, E1, E2, E3) \
        acc[0][HB] += E0.x * h##HB.x; acc[0][HB] += E0.y * h##HB.y; \
        acc[0][HB] += E0.z * h##HB.z; acc[0][HB] += E0.w * h##HB.w; \
        acc[1][HB] += E1.x * h##HB.x; acc[1][HB] += E1.y * h##HB.y; \
        acc[1][HB] += E1.z * h##HB.z; acc[1][HB] += E1.w * h##HB.w; \
        acc[2][HB] += E2.x * h##HB.x; acc[2][HB] += E2.y * h##HB.y; \
        acc[2][HB] += E2.z * h##HB.z; acc[2][HB] += E2.w * h##HB.w; \
        acc[3][HB] += E3.x * h##HB.x; acc[3][HB] += E3.y * h##HB.y; \
        acc[3][HB] += E3.z * h##HB.z; acc[3][HB] += E3.w * h##HB.w;

    // one iteration: prefetch e(C+1), stage chunk C+2, wait, 2 k-quad passes
    #define HALF(C, C00,C01,C10,C11,C20,C21,C30,C31, N00,N01,N10,N11,N20,N21,N30,N31) \
    { \
        const float* enx = ebase + (size_t)(((C) + 1) & (NCH - 1)) * CHF; \
        N00 = *reinterpret_cast<const float4*>(enx + 0 * DD); \
        N01 = *reinterpret_cast<const float4*>(enx + 0 * DD + 64); \
        N10 = *reinterpret_cast<const float4*>(enx + 1 * DD); \
        N11 = *reinterpret_cast<const float4*>(enx + 1 * DD + 64); \
        N20 = *reinterpret_cast<const float4*>(enx + 2 * DD); \
        N21 = *reinterpret_cast<const float4*>(enx + 2 * DD + 64); \
        N30 = *reinterpret_cast<const float4*>(enx + 3 * DD); \
        N31 = *reinterpret_cast<const float4*>(enx + 3 * DD + 64); \
        CBAR(); \
        { const size_t off = ((C) < NCH - 2) ? (size_t)((C) + 2) * CHF : 0; \
          GLDS(gsrcA + off, &hs[wb][bb0][0]); \
          GLDS(gsrcB + off, &hs[wb][bb0 + 2][0]); } \
        asm volatile("s_waitcnt vmcnt(20)" ::: "memory"); \
        { \
            float4 h0 = *reinterpret_cast<const float4*>(&hs[rb][bb0 + 0][kl << 2]); \
            float4 h1 = *reinterpret_cast<const float4*>(&hs[rb][bb0 + 1][kl << 2]); \
            float4 h2 = *reinterpret_cast<const float4*>(&hs[rb][bb0 + 2][kl << 2]); \
            float4 h3 = *reinterpret_cast<const float4*>(&hs[rb][bb0 + 3][kl << 2]); \
            PASSF(0, C00, C10, C20, C30) \
            PASSF(1, C00, C10, C20, C30) \
            PASSF(2, C00, C10, C20, C30) \
            PASSF(3, C00, C10, C20, C30) \
        } \
        { \
            float4 h0 = *reinterpret_cast<const float4*>(&hs[rb][bb0 + 0][64 + (kl << 2)]); \
            float4 h1 = *reinterpret_cast<const float4*>(&hs[rb][bb0 + 1][64 + (kl << 2)]); \
            float4 h2 = *reinterpret_cast<const float4*>(&hs[rb][bb0 + 2][64 + (kl << 2)]); \
            float4 h3 = *reinterpret_cast<const float4*>(&hs[rb][bb0 + 3][64 + (kl << 2)]); \
            PASSF(0, C01, C11, C21, C31) \
            PASSF(1, C01, C11, C21, C31) \
            PASSF(2, C01, C11, C21, C31) \
            PASSF(3, C01, C11, C21, C31) \
        } \
        rb = (rb == 2) ? 0 : rb + 1; \
        wb = (wb == 2) ? 0 : wb + 1; \
    }

    // NOTE: PASSF(HB,...) multiplies h-row HB by each v's e-quad; the e-quad
    // pair (C*0 then C*1) covers k = c*128 + {0..63, 64..127} at kl*4 — the
    // same per-accumulator ascending-k order as R8/R9's CH=64 chunks.
    #pragma unroll 1
    for (int d = 0; d < NCH / 2; ++d) {
        const int c0 = 2 * d;
        HALF(c0,     A00,A01,A10,A11,A20,A21,A30,A31, B00,B01,B10,B11,B20,B21,B30,B31)
        HALF(c0 + 1, B00,B01,B10,B11,B20,B21,B30,B31, A00,A01,A10,A11,A20,A21,A30,A31)
    }
    #undef HALF
    #undef PASSF

    // keep the tail prefetch loads alive (uniform vmem op count; rule #17)
    asm volatile("" :: "v"(A00.x), "v"(A01.x), "v"(A10.x), "v"(A11.x),
                       "v"(A20.x), "v"(A21.x), "v"(A30.x), "v"(A31.x));

    // reduce partial dots across the 16 k-lanes (identical tree to R8)
    #pragma unroll
    for (int v = 0; v < 4; ++v)
        #pragma unroll
        for (int b = 0; b < 4; ++b) {
            float a = acc[v][b];
            a += __shfl_xor(a, 1, 64);
            a += __shfl_xor(a, 2, 64);
            a += __shfl_xor(a, 4, 64);
            a += __shfl_xor(a, 8, 64);
            acc[v][b] = a;
        }

    if (kl == 0) {
        #pragma unroll
        for (int v = 0; v < 4; ++v)
            #pragma unroll
            for (int b = 0; b < 4; ++b) {
                float raw = acc[v][b];
                float l = tanhf(raw / 30.0f) * 30.0f;   // final logit softcapping
                l = l / temps[bb0 + b];                  // temperature
                lout[(vl << 2) + v][bb0 + b] = l;
            }
    }
    __syncthreads();
    {
        int b2  = tid >> 4;
        int vv2 = tid & 15;
        out[32 + (size_t)b2 * VV + vbase + vv2] = lout[vv2][b2];
    }
}

// ---------------- K2: per-row top-64 (prob-sorted, stable) + exact-RNG categorical ----------------
__global__ __launch_bounds__(1024) void sample_kernel(
    float* __restrict__ dout, const float* __restrict__ top_ps,
    const int* __restrict__ top_ks)
{
    const int b   = blockIdx.x;
    const int tid = threadIdx.x;
    const float* row = dout + 32 + (size_t)b * VV;

    __shared__ unsigned int hist[2048];            // 8KB
    __shared__ unsigned long long arr[NCAND];      // 32KB: (enc(p)<<32)|~idx
    __shared__ float red[1024];                    // 4KB
    __shared__ float m_sh;
    __shared__ unsigned int thresh_sh;
    __shared__ unsigned int cnt_sh;
    __shared__ float p_arr[64];
    __shared__ unsigned int idx_arr[64];
    __shared__ float S_sh;
    __shared__ unsigned long long keep_sh;

    for (int i = tid; i < 2048; i += 1024) hist[i] = 0u;
    for (int i = tid; i < NCAND; i += 1024) arr[i] = 0ull;
    if (tid == 0) cnt_sh = 0u;
    __syncthreads();

    // ---- pass A: row max + 11-bit float-order histogram ----
    float lmax = -INFINITY;
    for (int i = tid; i < VV; i += 1024) {
        float l = row[i];
        lmax = fmaxf(lmax, l);
        atomicAdd(&hist[enc_f32(l) >> 21], 1u);
    }
    red[tid] = lmax;
    __syncthreads();
    for (int s = 512; s > 0; s >>= 1) {
        if (tid < s) red[tid] = fmaxf(red[tid], red[tid + s]);
        __syncthreads();
    }
    if (tid == 0) {
        float m = red[0];
        m_sh = m;
        int t = (int)(enc_f32(m) >> 21);
        unsigned int cum = 0u;
        for (; t >= 0; --t) { cum += hist[t]; if (cum >= 64u) break; }
        if (t < 0) t = 0;
        thresh_sh = ((unsigned int)t) << 21;
    }
    __syncthreads();
    const float m = m_sh;
    const unsigned int thresh = thresh_sh;

    // ---- pass B: softmax denominator Z ----
    float z = 0.0f;
    for (int i = tid; i < VV; i += 1024) z += expf(row[i] - m);
    red[tid] = z;
    __syncthreads();
    for (int s = 512; s > 0; s >>= 1) {
        if (tid < s) red[tid] += red[tid + s];
        __syncthreads();
    }
    const float Z = red[0];
    __syncthreads();

    // ---- pass C: collect candidates keyed by (prob desc, idx asc) ----
    for (int i = tid; i < VV; i += 1024) {
        float l = row[i];
        if (enc_f32(l) >= thresh) {
            float p = expf(l - m) / Z;
            unsigned int slot = atomicAdd(&cnt_sh, 1u);
            if (slot < NCAND)
                arr[slot] = ((unsigned long long)enc_f32(p) << 32)
                          | (unsigned long long)(~(unsigned int)i);
        }
    }
    __syncthreads();

    // ---- bitonic sort, descending (zeros sink to the end) ----
    for (int k = 2; k <= NCAND; k <<= 1) {
        for (int j = k >> 1; j > 0; j >>= 1) {
            for (int t = tid; t < NCAND; t += 1024) {
                int ixj = t ^ j;
                if (ixj > t) {
                    unsigned long long a = arr[t], c = arr[ixj];
                    bool desc = ((t & k) == 0);
                    if (desc ? (a < c) : (a > c)) { arr[t] = c; arr[ixj] = a; }
                }
            }
            __syncthreads();
        }
    }

    // ---- decode top-64 ----
    if (tid < 64) {
        unsigned long long key = arr[tid];
        p_arr[tid]   = __uint_as_float((unsigned int)(key >> 32) & 0x7FFFFFFFu);
        idx_arr[tid] = ~((unsigned int)(key & 0xFFFFFFFFull));
    }
    __syncthreads();

    // ---- sequential fp32 cumsum + top-p/top-k keep mask (np order) ----
    if (tid == 0) {
        float cum = 0.0f, S = 0.0f;
        unsigned long long keep = 0ull;
        const float tp = top_ps[b];
        const int   tk = top_ks[b];
        for (int r = 0; r < 64; ++r) {
            float p = p_arr[r];
            cum = cum + p;
            float excl = cum - p;
            if (!(excl > tp) && (r < tk)) { keep |= (1ull << r); S = S + p; }
        }
        S_sh = S; keep_sh = keep;
    }
    __syncthreads();

    // ---- gumbel-max over kept set (exact jax.random.categorical(key(42))) ----
    if (tid < 64) {
        unsigned long long pk = 0ull;
        if ((keep_sh >> tid) & 1ull) {
            float q  = p_arr[tid] / S_sh;
            float lp = logf(q);
            unsigned int idx = idx_arr[tid];
            float g = gumbel_at((unsigned int)b * (unsigned int)VV + idx);
            float vf = lp + g;
            pk = ((unsigned long long)enc_f32(vf) << 32)
               | (unsigned long long)(~idx);
        }
        for (int off = 1; off < 64; off <<= 1) {
            unsigned long long o = __shfl_xor(pk, off, 64);
            if (o > pk) pk = o;
        }
        if (tid == 0) {
            unsigned int token = ~((unsigned int)(pk & 0xFFFFFFFFull));
            dout[b] = (float)token;
        }
    }
}

extern "C" void kernel_launch(void* const* d_in, const int* in_sizes, int n_in,
                              void* d_out, int out_size, void* d_ws, size_t ws_size,
                              hipStream_t stream) {
    const float* emb   = (const float*)d_in[0];
    const float* hid   = (const float*)d_in[1];
    const int*   pos   = (const int*)d_in[2];
    const float* temps = (const float*)d_in[3];
    const float* tps   = (const float*)d_in[4];
    const int*   tks   = (const int*)d_in[5];
    float* out = (float*)d_out;

    gemv_kernel<<<dim3(VV / 16), dim3(512), 0, stream>>>(emb, hid, pos, temps, out);
    sample_kernel<<<dim3(BB), dim3(1024), 0, stream>>>(out, tps, tks);
}